// Round 10
// baseline (147.076 us; speedup 1.0000x reference)
//
#include <hip/hip_runtime.h>
#include <hip/hip_fp16.h>

#define NN 100000
#define NE 1250000
#define D 64
#define MT 6250                 // NN / 16 M-tiles (exact, no tail)
#define RP_BLOCKS 4883          // ceil(NE/256) blocks for rowptr part of k_prep
#define ANB 32                  // aggr nodes per block (8 lanes/node)
#define NSL 4                   // column slices (16 cols = 32 B fp16 each)
#define MAXLE 2048              // LDS edge cache; block mean ~400 edges

typedef _Float16 h8 __attribute__((ext_vector_type(8)));
typedef float f4 __attribute__((ext_vector_type(4)));

__device__ inline float2 cvt2(unsigned u) {
    __half2 h = __builtin_bit_cast(__half2, u);
    return __half22float2(h);
}

// ---------------------------------------------------------------------------
// k_prep: blocks [0, RP_BLOCKS) build row_ptr from sorted dst.
// Blocks [RP_BLOCKS, RP_BLOCKS+64) pack W_self|W_neigh into per-lane MFMA
// B-fragments split into fp16 hi + fp16 residual (lo). (unchanged, round 8)
// ---------------------------------------------------------------------------
__global__ __launch_bounds__(256) void k_prep(const int* __restrict__ dst,
                                              int* __restrict__ row_ptr,
                                              const float* __restrict__ Ws,
                                              const float* __restrict__ Wn,
                                              __half* __restrict__ Wp) {
    if (blockIdx.x < RP_BLOCKS) {
        const int i = blockIdx.x * 256 + threadIdx.x;
        if (i >= NE) return;
        const int d = dst[i];
        const int prev = (i == 0) ? -1 : dst[i - 1];
        for (int v = prev + 1; v <= d; ++v) row_ptr[v] = i;
        if (i == NE - 1) {
            for (int v = d + 1; v <= NN; ++v) row_ptr[v] = NE;
        }
    } else {
        const int id = (blockIdx.x - RP_BLOCKS) * 256 + threadIdx.x; // 0..16383
        const int p = id >> 13;        // 0 = hi, 1 = lo
        const int r = id & 8191;
        const int i = r & 7;
        const int l = (r >> 3) & 63;
        const int f = (r >> 9) & 1;
        const int t = r >> 10;         // 0..7
        const int k = f * 32 + ((l >> 4) * 8) + i;
        const int c = (t & 3) * 16 + (l & 15);
        const float v = ((t < 4) ? Ws : Wn)[k * D + c];
        const _Float16 hi = (_Float16)v;
        const _Float16 out = p ? (_Float16)(v - (float)hi) : hi;
        Wp[p * 8192 + r] = __builtin_bit_cast(__half, out);
    }
}

// ---------------------------------------------------------------------------
// k_mm: split-fp16 MFMA GEMM, one x pass:
//   z = x@Wself + b -> d_out (fp32, row-major)
//   y = x@Wneigh    -> ws as SLICE-MAJOR fp16 y_t[4][NN][16 cols]:
//       the aggregation gather is per-XCD L2-compulsory-miss bound (round-6/9
//       counters); 3.2 MB slices are L2-resident per XCD. Each N-tile t>=4 is
//       exactly one slice (s = t&3), so only the store address changes.
// acc = Al*Bh + Ah*Bl + Ah*Bh, fp32 accumulate: error ~2^-21.
// ---------------------------------------------------------------------------
__global__ __launch_bounds__(256) void k_mm(const float* __restrict__ x,
                                            const __half* __restrict__ Wp,
                                            const float* __restrict__ b,
                                            float* __restrict__ z,
                                            __half* __restrict__ yt) {
    const int lane = threadIdx.x & 63;
    const int mt = blockIdx.x * 4 + (threadIdx.x >> 6);
    if (mt >= MT) return;
    const int row = lane & 15;
    const int kg = lane >> 4;               // 0..3
    const float* __restrict__ xr = x + (size_t)(mt * 16 + row) * D + kg * 8;

    const float4 v0 = *(const float4*)(xr);
    const float4 v1 = *(const float4*)(xr + 4);
    const float4 v2 = *(const float4*)(xr + 32);
    const float4 v3 = *(const float4*)(xr + 36);

    const float xf0[8] = {v0.x, v0.y, v0.z, v0.w, v1.x, v1.y, v1.z, v1.w};
    const float xf1[8] = {v2.x, v2.y, v2.z, v2.w, v3.x, v3.y, v3.z, v3.w};
    h8 ah0, al0, ah1, al1;
    #pragma unroll
    for (int i = 0; i < 8; ++i) {
        const _Float16 h0 = (_Float16)xf0[i];
        ah0[i] = h0;
        al0[i] = (_Float16)(xf0[i] - (float)h0);
        const _Float16 h1 = (_Float16)xf1[i];
        ah1[i] = h1;
        al1[i] = (_Float16)(xf1[i] - (float)h1);
    }

    const _Float16* __restrict__ wp = (const _Float16*)Wp;
    #pragma unroll
    for (int t = 0; t < 8; ++t) {
        const h8 bh0 = *(const h8*)(wp + ((t * 2 + 0) * 64 + lane) * 8);
        const h8 bh1 = *(const h8*)(wp + ((t * 2 + 1) * 64 + lane) * 8);
        const h8 bl0 = *(const h8*)(wp + 8192 + ((t * 2 + 0) * 64 + lane) * 8);
        const h8 bl1 = *(const h8*)(wp + 8192 + ((t * 2 + 1) * 64 + lane) * 8);
        f4 acc = {0.f, 0.f, 0.f, 0.f};
        acc = __builtin_amdgcn_mfma_f32_16x16x32_f16(al0, bh0, acc, 0, 0, 0);
        acc = __builtin_amdgcn_mfma_f32_16x16x32_f16(al1, bh1, acc, 0, 0, 0);
        acc = __builtin_amdgcn_mfma_f32_16x16x32_f16(ah0, bl0, acc, 0, 0, 0);
        acc = __builtin_amdgcn_mfma_f32_16x16x32_f16(ah1, bl1, acc, 0, 0, 0);
        acc = __builtin_amdgcn_mfma_f32_16x16x32_f16(ah0, bh0, acc, 0, 0, 0);
        acc = __builtin_amdgcn_mfma_f32_16x16x32_f16(ah1, bh1, acc, 0, 0, 0);

        const int r0 = mt * 16 + kg * 4;
        if (t < 4) {
            const int col = (t & 3) * 16 + (lane & 15);
            const float bb = b[col];
            #pragma unroll
            for (int reg = 0; reg < 4; ++reg)
                z[(size_t)(r0 + reg) * D + col] = acc[reg] + bb;
        } else {
            const int s = t & 3;             // this N-tile IS slice s
            #pragma unroll
            for (int reg = 0; reg < 4; ++reg)
                yt[((size_t)s * NN + r0 + reg) * 16 + (lane & 15)] =
                    __float2half(acc[reg]);
        }
    }
}

// ---------------------------------------------------------------------------
// k_aggr v5: slice-partitioned gather.
//   block b -> slice s = b % NSL, node group g = b / NSL.
//   Since blocks round-robin XCDs (bid % 8), slice s runs only on XCDs
//   {s, s+4}: each XCD's gather working set = one 3.2 MB slice, L2-resident.
// Thread layout: 8 lanes per node (lane q = u32 word = 2 fp16 cols of the
// slice), 32 nodes per block. Per-lane PRIVATE accumulation (zero shuffles),
// 8 edges in flight per node; src staged in LDS (round-9).
// out[v][s*16 + :16] += mean over edges (z already there from k_mm).
// Slices touch disjoint columns -> no cross-block races.
// ---------------------------------------------------------------------------
__global__ __launch_bounds__(256) void k_aggr(const __half* __restrict__ yt,
                                              const int* __restrict__ src,
                                              const int* __restrict__ row_ptr,
                                              float* __restrict__ out) {
    __shared__ int s_src[MAXLE];
    __shared__ int s_rp[ANB + 1];
    const int tid = threadIdx.x;
    const int s  = blockIdx.x & (NSL - 1);
    const int v0 = (blockIdx.x >> 2) * ANB;   // 3125 groups * 32 = NN exactly

    if (tid <= ANB) s_rp[tid] = row_ptr[v0 + tid];
    __syncthreads();
    const int base = s_rp[0];
    const int cnt = s_rp[ANB] - base;
    const bool fits = (cnt <= MAXLE);         // mean 400; 2048 is far-tail safe
    if (fits) {
        for (int i = tid; i < cnt; i += 256) s_src[i] = src[base + i];
    }
    __syncthreads();

    const int node = tid >> 3;                // 0..31
    const int q    = tid & 7;                 // u32 word within 32 B slice row
    const int v    = v0 + node;
    const int lo = s_rp[node];
    const int hi = s_rp[node + 1];
    const int deg = hi - lo;

    const unsigned* __restrict__ yrow = (const unsigned*)yt + (size_t)s * NN * 8 + q;

    float a0 = 0.0f, a1 = 0.0f;
    if (deg > 0) {
        const int last = hi - 1;
        if (fits) {
            for (int e = lo; e < hi; e += 8) {
                unsigned r[8];
                #pragma unroll
                for (int u = 0; u < 8; ++u) {
                    const int sv = s_src[min(e + u, last) - base];  // lgkm only
                    r[u] = yrow[(size_t)sv * 8];       // 8 rows in flight
                }
                #pragma unroll
                for (int u = 0; u < 8; ++u) {
                    if (e + u < hi) {
                        const float2 f = cvt2(r[u]);
                        a0 += f.x; a1 += f.y;
                    }
                }
            }
        } else {  // correctness fallback (practically never taken)
            for (int e = lo; e < hi; e += 8) {
                unsigned r[8];
                #pragma unroll
                for (int u = 0; u < 8; ++u) {
                    const int sv = src[min(e + u, last)];
                    r[u] = yrow[(size_t)sv * 8];
                }
                #pragma unroll
                for (int u = 0; u < 8; ++u) {
                    if (e + u < hi) {
                        const float2 f = cvt2(r[u]);
                        a0 += f.x; a1 += f.y;
                    }
                }
            }
        }
    }
    const float inv = (deg > 0) ? 1.0f / (float)deg : 0.0f;
    // 8 lanes x 8 B = 64 B contiguous per node
    float2* op = (float2*)(out + (size_t)v * D + s * 16 + q * 2);
    float2 o = *op;                            // z from k_mm
    o.x += a0 * inv;
    o.y += a1 * inv;
    *op = o;
}

extern "C" void kernel_launch(void* const* d_in, const int* in_sizes, int n_in,
                              void* d_out, int out_size, void* d_ws, size_t ws_size,
                              hipStream_t stream) {
    const float* x      = (const float*)d_in[0];
    const float* Wself  = (const float*)d_in[1];
    const float* Wneigh = (const float*)d_in[2];
    const float* b      = (const float*)d_in[3];
    const int*   src    = (const int*)d_in[4];
    const int*   dst    = (const int*)d_in[5];
    float* out = (float*)d_out;

    // ws layout: y_t fp16 [4][NN][16] | row_ptr | Wp (hi 8192 + lo 8192)
    __half* yt = (__half*)d_ws;
    const size_t yb = (size_t)NN * D * 2;
    int* row_ptr = (int*)((char*)d_ws + yb);
    const size_t rpb = (((size_t)(NN + 1) * 4) + 15) & ~(size_t)15;
    __half* Wp = (__half*)((char*)d_ws + yb + rpb);

    k_prep<<<RP_BLOCKS + 64, 256, 0, stream>>>(dst, row_ptr, Wself, Wneigh, Wp);
    k_mm<<<(MT + 3) / 4, 256, 0, stream>>>(x, Wp, b, out, yt);
    // (NN/ANB) node groups x NSL slices; slice = bid % NSL pins to XCD pair
    k_aggr<<<(NN / ANB) * NSL, 256, 0, stream>>>(yt, src, row_ptr, out);
}

// Round 11
// 132.958 us; speedup vs baseline: 1.1062x; 1.1062x over previous
//
#include <hip/hip_runtime.h>
#include <hip/hip_fp16.h>

#define NN 100000
#define NE 1250000
#define D 64
#define MT 6250                 // NN / 16 M-tiles (exact, no tail)
#define RP_BLOCKS 4883          // ceil(NE/256) blocks for rowptr part of k_prep
#define ANB 8                   // aggr nodes per block (4 waves x 2)
#define MAXLE 2048              // LDS edge cache; block mean ~100 edges

typedef _Float16 h8 __attribute__((ext_vector_type(8)));
typedef float f4 __attribute__((ext_vector_type(4)));

__device__ inline float2 cvt2(unsigned u) {
    __half2 h = __builtin_bit_cast(__half2, u);
    return __half22float2(h);
}

// ---------------------------------------------------------------------------
// k_prep: blocks [0, RP_BLOCKS) build row_ptr from sorted dst.
// Blocks [RP_BLOCKS, RP_BLOCKS+64) pack W_self|W_neigh into per-lane MFMA
// B-fragments split into fp16 hi + fp16 residual (lo). (unchanged, round 8)
// ---------------------------------------------------------------------------
__global__ __launch_bounds__(256) void k_prep(const int* __restrict__ dst,
                                              int* __restrict__ row_ptr,
                                              const float* __restrict__ Ws,
                                              const float* __restrict__ Wn,
                                              __half* __restrict__ Wp) {
    if (blockIdx.x < RP_BLOCKS) {
        const int i = blockIdx.x * 256 + threadIdx.x;
        if (i >= NE) return;
        const int d = dst[i];
        const int prev = (i == 0) ? -1 : dst[i - 1];
        for (int v = prev + 1; v <= d; ++v) row_ptr[v] = i;
        if (i == NE - 1) {
            for (int v = d + 1; v <= NN; ++v) row_ptr[v] = NE;
        }
    } else {
        const int id = (blockIdx.x - RP_BLOCKS) * 256 + threadIdx.x; // 0..16383
        const int p = id >> 13;        // 0 = hi, 1 = lo
        const int r = id & 8191;
        const int i = r & 7;
        const int l = (r >> 3) & 63;
        const int f = (r >> 9) & 1;
        const int t = r >> 10;         // 0..7
        const int k = f * 32 + ((l >> 4) * 8) + i;
        const int c = (t & 3) * 16 + (l & 15);
        const float v = ((t < 4) ? Ws : Wn)[k * D + c];
        const _Float16 hi = (_Float16)v;
        const _Float16 out = p ? (_Float16)(v - (float)hi) : hi;
        Wp[p * 8192 + r] = __builtin_bit_cast(__half, out);
    }
}

// ---------------------------------------------------------------------------
// k_mm: split-fp16 MFMA GEMM, one x pass:
//   z = x@Wself + b -> d_out (fp32, row-major)
//   y = x@Wneigh    -> ws (fp16, ROW-major — round-10's slice-major L2 bet
//       failed: streaming out-RMW evicts slices; reverted)
// acc = Al*Bh + Ah*Bl + Ah*Bh, fp32 accumulate: error ~2^-21. (round 8)
// ---------------------------------------------------------------------------
__global__ __launch_bounds__(256) void k_mm(const float* __restrict__ x,
                                            const __half* __restrict__ Wp,
                                            const float* __restrict__ b,
                                            float* __restrict__ z,
                                            __half* __restrict__ y) {
    const int lane = threadIdx.x & 63;
    const int mt = blockIdx.x * 4 + (threadIdx.x >> 6);
    if (mt >= MT) return;
    const int row = lane & 15;
    const int kg = lane >> 4;               // 0..3
    const float* __restrict__ xr = x + (size_t)(mt * 16 + row) * D + kg * 8;

    const float4 v0 = *(const float4*)(xr);
    const float4 v1 = *(const float4*)(xr + 4);
    const float4 v2 = *(const float4*)(xr + 32);
    const float4 v3 = *(const float4*)(xr + 36);

    const float xf0[8] = {v0.x, v0.y, v0.z, v0.w, v1.x, v1.y, v1.z, v1.w};
    const float xf1[8] = {v2.x, v2.y, v2.z, v2.w, v3.x, v3.y, v3.z, v3.w};
    h8 ah0, al0, ah1, al1;
    #pragma unroll
    for (int i = 0; i < 8; ++i) {
        const _Float16 h0 = (_Float16)xf0[i];
        ah0[i] = h0;
        al0[i] = (_Float16)(xf0[i] - (float)h0);
        const _Float16 h1 = (_Float16)xf1[i];
        ah1[i] = h1;
        al1[i] = (_Float16)(xf1[i] - (float)h1);
    }

    const _Float16* __restrict__ wp = (const _Float16*)Wp;
    #pragma unroll
    for (int t = 0; t < 8; ++t) {
        const h8 bh0 = *(const h8*)(wp + ((t * 2 + 0) * 64 + lane) * 8);
        const h8 bh1 = *(const h8*)(wp + ((t * 2 + 1) * 64 + lane) * 8);
        const h8 bl0 = *(const h8*)(wp + 8192 + ((t * 2 + 0) * 64 + lane) * 8);
        const h8 bl1 = *(const h8*)(wp + 8192 + ((t * 2 + 1) * 64 + lane) * 8);
        f4 acc = {0.f, 0.f, 0.f, 0.f};
        acc = __builtin_amdgcn_mfma_f32_16x16x32_f16(al0, bh0, acc, 0, 0, 0);
        acc = __builtin_amdgcn_mfma_f32_16x16x32_f16(al1, bh1, acc, 0, 0, 0);
        acc = __builtin_amdgcn_mfma_f32_16x16x32_f16(ah0, bl0, acc, 0, 0, 0);
        acc = __builtin_amdgcn_mfma_f32_16x16x32_f16(ah1, bl1, acc, 0, 0, 0);
        acc = __builtin_amdgcn_mfma_f32_16x16x32_f16(ah0, bh0, acc, 0, 0, 0);
        acc = __builtin_amdgcn_mfma_f32_16x16x32_f16(ah1, bh1, acc, 0, 0, 0);

        const int col = (t & 3) * 16 + (lane & 15);
        const int r0 = mt * 16 + kg * 4;
        if (t < 4) {
            const float bb = b[col];
            #pragma unroll
            for (int reg = 0; reg < 4; ++reg)
                z[(size_t)(r0 + reg) * D + col] = acc[reg] + bb;
        } else {
            #pragma unroll
            for (int reg = 0; reg < 4; ++reg)
                y[(size_t)(r0 + reg) * D + col] = __float2half(acc[reg]);
        }
    }
}

// ---------------------------------------------------------------------------
// k_aggr v6: out[v][:] = z[v][:] + mean_{u in N(v)} y_fp16[u][:]
// Round-9 structure (row-major y, LDS src staging) but uint2 loads:
//   half-wave (one node) = 2 slots x 16 words; each load instruction covers
//   2 edge rows (slot 0/1), 8 B/lane. 8 unrolled instrs = 16 edges in
//   flight per node (2x round-9's MLP, half the instructions per edge).
// s_src reads are 2-address-per-half-wave broadcasts (conflict-free).
// Slot partials combined by 4 shfl_xor ONCE per node; slot-0 lanes do the
// 256 B coalesced z-RMW into d_out.
// ---------------------------------------------------------------------------
__global__ __launch_bounds__(256) void k_aggr(const __half* __restrict__ y,
                                              const int* __restrict__ src,
                                              const int* __restrict__ row_ptr,
                                              float* __restrict__ out) {
    __shared__ int s_src[MAXLE];
    __shared__ int s_rp[ANB + 1];
    const int tid = threadIdx.x;
    const int v0 = blockIdx.x * ANB;          // 12500 blocks * 8 = NN exactly

    if (tid <= ANB) s_rp[tid] = row_ptr[v0 + tid];
    __syncthreads();
    const int base = s_rp[0];
    const int cnt = s_rp[ANB] - base;
    const bool fits = (cnt <= MAXLE);         // mean 100; 2048 is far-tail safe
    if (fits) {
        for (int i = tid; i < cnt; i += 256) s_src[i] = src[base + i];
    }
    __syncthreads();

    const int lane = tid & 63;
    const int half = lane >> 5;               // which of the wave's 2 nodes
    const int slot = (lane >> 4) & 1;         // edge slot within half-wave
    const int word = lane & 15;               // uint2 (4 fp16 cols) within row
    const int node = (tid >> 6) * 2 + half;   // 0..7 within block
    const int v    = v0 + node;
    const int lo = s_rp[node];
    const int hi = s_rp[node + 1];
    const int deg = hi - lo;

    const uint2* __restrict__ yw = (const uint2*)y;   // 16 uint2 per 128 B row

    float a0 = 0.f, a1 = 0.f, a2 = 0.f, a3 = 0.f;
    if (deg > 0) {
        const int last = hi - 1;
        if (fits) {
            for (int e = lo; e < hi; e += 16) {
                uint2 r[8];
                #pragma unroll
                for (int u = 0; u < 8; ++u) {
                    const int sv = s_src[min(e + u * 2 + slot, last) - base];
                    r[u] = yw[(size_t)sv * 16 + word];   // 16 rows in flight
                }
                #pragma unroll
                for (int u = 0; u < 8; ++u) {
                    if (e + u * 2 + slot < hi) {
                        const float2 f0 = cvt2(r[u].x);
                        const float2 f1 = cvt2(r[u].y);
                        a0 += f0.x; a1 += f0.y; a2 += f1.x; a3 += f1.y;
                    }
                }
            }
        } else {  // correctness fallback (practically never taken)
            for (int e = lo; e < hi; e += 16) {
                uint2 r[8];
                #pragma unroll
                for (int u = 0; u < 8; ++u) {
                    const int sv = src[min(e + u * 2 + slot, last)];
                    r[u] = yw[(size_t)sv * 16 + word];
                }
                #pragma unroll
                for (int u = 0; u < 8; ++u) {
                    if (e + u * 2 + slot < hi) {
                        const float2 f0 = cvt2(r[u].x);
                        const float2 f1 = cvt2(r[u].y);
                        a0 += f0.x; a1 += f0.y; a2 += f1.x; a3 += f1.y;
                    }
                }
            }
        }
    }
    // combine slot pair (lane l <-> l^16 hold the same 4 cols, other edges)
    a0 += __shfl_xor(a0, 16);
    a1 += __shfl_xor(a1, 16);
    a2 += __shfl_xor(a2, 16);
    a3 += __shfl_xor(a3, 16);
    if (slot == 0) {                 // 16 lanes x 16 B = 256 B per node
        const float inv = (deg > 0) ? 1.0f / (float)deg : 0.0f;
        float4* op = (float4*)(out + (size_t)v * D + word * 4);
        float4 o = *op;              // z from k_mm
        o.x += a0 * inv; o.y += a1 * inv;
        o.z += a2 * inv; o.w += a3 * inv;
        *op = o;
    }
}

extern "C" void kernel_launch(void* const* d_in, const int* in_sizes, int n_in,
                              void* d_out, int out_size, void* d_ws, size_t ws_size,
                              hipStream_t stream) {
    const float* x      = (const float*)d_in[0];
    const float* Wself  = (const float*)d_in[1];
    const float* Wneigh = (const float*)d_in[2];
    const float* b      = (const float*)d_in[3];
    const int*   src    = (const int*)d_in[4];
    const int*   dst    = (const int*)d_in[5];
    float* out = (float*)d_out;

    // ws layout: y fp16 [NN][64] | row_ptr | Wp (hi 8192 + lo 8192 halves)
    __half* y = (__half*)d_ws;
    const size_t yb = (size_t)NN * D * 2;
    int* row_ptr = (int*)((char*)d_ws + yb);
    const size_t rpb = (((size_t)(NN + 1) * 4) + 15) & ~(size_t)15;
    __half* Wp = (__half*)((char*)d_ws + yb + rpb);

    k_prep<<<RP_BLOCKS + 64, 256, 0, stream>>>(dst, row_ptr, Wself, Wneigh, Wp);
    k_mm<<<(MT + 3) / 4, 256, 0, stream>>>(x, Wp, b, out, y);
    k_aggr<<<NN / ANB, 256, 0, stream>>>(y, src, row_ptr, out);
}